// Round 5
// baseline (1281.889 us; speedup 1.0000x reference)
//
#include <hip/hip_runtime.h>
#include <stdint.h>

// ---------------- problem constants ----------------
#define T_TOKENS 4096
#define D_HID    2048
#define D_INT    4096
#define N_EXP    8
#define TOPK     4
#define NFLAT    (T_TOKENS*TOPK)      // 16384 routed pairs
#define BMT      256                  // M tile
#define MAXPAD   (NFLAT + N_EXP*BMT)  // 18432 worst-case padded rows
#define MT2      (MAXPAD/BMT)         // 72 M-tiles

// ---------------- ws layout (bytes) ----------------
#define OFF_PTOK 0ull
#define OFF_PWT  73728ull
#define OFF_CNT  147456ull
#define OFF_TOFF 147712ull
#define OFF_SEG  155904ull
#define OFF_XB   262144ull                  // 4096*2048*2 = 16,777,216
#define OFF_ACT  17039360ull                // 18432*4096*2 = 150,994,944
#define OFF_W    168034304ull               // max(wgu_b 268,435,456, wd_b 134,217,728)
// total need ~436.5 MB (proven available in round 2: >=562 MB)

typedef float f32x4  __attribute__((ext_vector_type(4)));
typedef short bf16x8 __attribute__((ext_vector_type(8)));

__device__ __forceinline__ unsigned short f2bf(float f) {
    unsigned int u = __float_as_uint(f);
    u += 0x7fffu + ((u >> 16) & 1u);      // RNE
    return (unsigned short)(u >> 16);
}

__device__ __forceinline__ void gload_lds16(const void* g, void* l) {
    __builtin_amdgcn_global_load_lds((const __attribute__((address_space(1))) void*)g,
                                     (__attribute__((address_space(3))) void*)l,
                                     16, 0, 0);
}

// XCD-bijective chunk swizzle (m204)
__device__ __forceinline__ int xcd_logical(int hw, int nwg) {
    int q = nwg >> 3, r = nwg & 7;
    int xc = hw & 7, sl = hw >> 3;
    return (xc < r ? xc * (q + 1) : r * (q + 1) + (xc - r) * q) + sl;
}

// ---------------- kernel 0: cast x -> bf16, zero out ----------------
__global__ void k_prep(const float* __restrict__ x, unsigned short* __restrict__ xb,
                       float* __restrict__ out) {
    int i = blockIdx.x * 256 + threadIdx.x;          // float4 units, exact grid (8192)
    float4 v = ((const float4*)x)[i];
    ushort4 h;
    h.x = f2bf(v.x); h.y = f2bf(v.y); h.z = f2bf(v.z); h.w = f2bf(v.w);
    ((ushort4*)xb)[i] = h;
    ((float4*)out)[i] = make_float4(0.f, 0.f, 0.f, 0.f);
}

// ---------------- generic fp32 -> bf16 cast (grid = n4/256) ----------------
__global__ void k_cast(const float* __restrict__ src, unsigned short* __restrict__ dst) {
    size_t i = (size_t)blockIdx.x * 256 + threadIdx.x;   // float4 index
    float4 v = ((const float4*)src)[i];
    ushort4 h;
    h.x = f2bf(v.x); h.y = f2bf(v.y); h.z = f2bf(v.z); h.w = f2bf(v.w);
    ((ushort4*)dst)[i] = h;
}

// ---------------- routing: deterministic compaction ----------------
__global__ void k_count(const int* __restrict__ te, int* __restrict__ counts,
                        int* __restrict__ toff) {
    int e = blockIdx.x, t = threadIdx.x;
    int cnt = 0;
    int base = t * 64;
    for (int i = 0; i < 64; i++) cnt += (te[base + i] == e);
    __shared__ int s[256];
    s[t] = cnt; __syncthreads();
    int incl = cnt;
    for (int off = 1; off < 256; off <<= 1) {
        int tmp = (t >= off) ? s[t - off] : 0;
        __syncthreads();
        incl += tmp; s[t] = incl;
        __syncthreads();
    }
    toff[e * 256 + t] = incl - cnt;
    if (t == 255) counts[e] = incl;
}

__global__ void k_fill(const int* __restrict__ te, const float* __restrict__ tw,
                       const int* __restrict__ counts, const int* __restrict__ toff,
                       int* __restrict__ ptok, float* __restrict__ pwt, int* __restrict__ seg) {
    int e = blockIdx.x, t = threadIdx.x;
    int segs[9]; int a = 0;
    #pragma unroll
    for (int j = 0; j < 8; j++) { segs[j] = a; a += (counts[j] + BMT - 1) & ~(BMT - 1); }
    segs[8] = a;
    if (e == 0 && t == 0) { for (int j = 0; j < 9; j++) seg[j] = segs[j]; }
    int base = segs[e] + toff[e * 256 + t];
    int rank = 0;
    for (int i = t * 64; i < (t + 1) * 64; i++) {
        if (te[i] == e) { ptok[base + rank] = i >> 2; pwt[base + rank] = tw[i]; rank++; }
    }
    int cnt = counts[e], pc = (cnt + BMT - 1) & ~(BMT - 1);
    for (int i = cnt + t; i < pc; i += 256) { ptok[segs[e] + i] = -1; pwt[segs[e] + i] = 0.f; }
}

// =====================================================================
// 256x256x32 pipelined GEMM core, round-5 schedule:
//  - outer ring unchanged from validated round-4: 4 x 32KB LDS ring,
//    prefetch distance 3, vmcnt(12/8/4/0), 2 s_barrier per K-step
//  - NEW: inside the K-step, reads issue in pinned order (bf0-3,af0-1 |
//    af2-7) and MFMA runs in 4 clusters of 8 gated by counted
//    lgkmcnt(6/4/2/0) -> ds_read overlaps MFMA (DS completes in-order).
//  - barrier #2 sits after lgkmcnt(0), BEFORE the last cluster, so the
//    next STAGE issue overlaps the tail MFMAs. Slot-reuse proof intact:
//    STAGE(kt+1) targets slot kt&3 and issues only after bar#2 (= all
//    waves' reads of slot kt&3 complete).
// =====================================================================

#define MFMA_2M(M0, M1) \
    _Pragma("unroll") for (int n_ = 0; n_ < 4; ++n_) \
        acc[M0][n_] = __builtin_amdgcn_mfma_f32_16x16x32_bf16(af[M0], bf[n_], acc[M0][n_], 0, 0, 0); \
    _Pragma("unroll") for (int n_ = 0; n_ < 4; ++n_) \
        acc[M1][n_] = __builtin_amdgcn_mfma_f32_16x16x32_bf16(af[M1], bf[n_], acc[M1][n_], 0, 0, 0);

#define KSTEP(VMS) \
  asm volatile("s_waitcnt vmcnt(" VMS ")" ::: "memory"); \
  __builtin_amdgcn_s_barrier(); \
  __builtin_amdgcn_sched_barrier(0); \
  { \
    const char* pT = ldsc + (cb << 15); \
    bf16x8 af[8], bf[4]; \
    _Pragma("unroll") for (int n_ = 0; n_ < 4; ++n_) \
        bf[n_] = *(const bf16x8*)(pT + b_off + n_ * 1024); \
    af[0] = *(const bf16x8*)(pT + a_off); \
    af[1] = *(const bf16x8*)(pT + a_off + 1024); \
    __builtin_amdgcn_sched_barrier(0); \
    _Pragma("unroll") for (int m_ = 2; m_ < 8; ++m_) \
        af[m_] = *(const bf16x8*)(pT + a_off + m_ * 1024); \
    __builtin_amdgcn_sched_barrier(0); \
    asm volatile("s_waitcnt lgkmcnt(6)" ::: "memory"); \
    __builtin_amdgcn_sched_barrier(0); \
    __builtin_amdgcn_s_setprio(1); \
    MFMA_2M(0, 1) \
    __builtin_amdgcn_s_setprio(0); \
    asm volatile("s_waitcnt lgkmcnt(4)" ::: "memory"); \
    __builtin_amdgcn_sched_barrier(0); \
    __builtin_amdgcn_s_setprio(1); \
    MFMA_2M(2, 3) \
    __builtin_amdgcn_s_setprio(0); \
    asm volatile("s_waitcnt lgkmcnt(2)" ::: "memory"); \
    __builtin_amdgcn_sched_barrier(0); \
    __builtin_amdgcn_s_setprio(1); \
    MFMA_2M(4, 5) \
    __builtin_amdgcn_s_setprio(0); \
    asm volatile("s_waitcnt lgkmcnt(0)" ::: "memory"); \
    __builtin_amdgcn_sched_barrier(0); \
    __builtin_amdgcn_s_barrier(); \
    __builtin_amdgcn_s_setprio(1); \
    MFMA_2M(6, 7) \
    __builtin_amdgcn_s_setprio(0); \
    cb = (cb + 1) & 3; \
  }

// ---------------- GEMM1: act = silu(gate)*up, h = xb @ Wgu^T ----------------
// grid 2304 = 32 nb (128 inter-cols each) x 72 mb
__global__ void __launch_bounds__(512, 2)
k_g1(const unsigned short* __restrict__ xb, const unsigned short* __restrict__ wgu_b,
     const int* __restrict__ ptok, const int* __restrict__ seg,
     unsigned short* __restrict__ act) {
    extern __shared__ char smem[];
    char* ldsw = smem; const char* ldsc = smem;
    int logical = xcd_logical(blockIdx.x, 2304);
    int nb = logical / MT2, mb = logical % MT2;
    if (mb * BMT >= seg[8]) return;
    int e = 0;
    #pragma unroll
    for (int j = 1; j < 8; ++j) if (seg[j] <= mb * BMT) e = j;
    int tid = threadIdx.x, w = tid >> 6, l = tid & 63;
    int wr = w >> 2, wc = w & 3;

    // ---- stage setup: 4 gloads/thread/K-tile ----
    int g = (l & 3) ^ ((l >> 3) & 3);            // pre-swizzled source chunk
    int r0 = w * 16 + (l >> 2), r1 = 128 + r0;   // rows within tile
    int t0 = ptok[mb * BMT + r0]; if (t0 < 0) t0 = 0;
    int t1 = ptok[mb * BMT + r1]; if (t1 < 0) t1 = 0;
    const char* pa0 = (const char*)xb + (size_t)t0 * 4096 + g * 16;
    const char* pa1 = (const char*)xb + (size_t)t1 * 4096 + g * 16;
    int wcr0 = r0 >> 6, j0 = r0 & 63;
    int wcr1 = r1 >> 6, j1 = r1 & 63;
    int gr0 = (j0 < 32) ? (nb * 128 + wcr0 * 32 + j0) : (D_INT + nb * 128 + wcr0 * 32 + j0 - 32);
    int gr1 = (j1 < 32) ? (nb * 128 + wcr1 * 32 + j1) : (D_INT + nb * 128 + wcr1 * 32 + j1 - 32);
    const char* wbase = (const char*)wgu_b + (size_t)e * 8192 * 4096;
    const char* pb0 = wbase + (size_t)gr0 * 4096 + g * 16;
    const char* pb1 = wbase + (size_t)gr1 * 4096 + g * 16;
    int dA0 = w * 1024, dA1 = 8192 + w * 1024;
    int dB0 = 16384 + w * 1024, dB1 = 24576 + w * 1024;
    int sb = 0;
    auto STAGE = [&]() {
        char* d = ldsw + (sb << 15);
        gload_lds16(pa0, d + dA0); gload_lds16(pa1, d + dA1);
        gload_lds16(pb0, d + dB0); gload_lds16(pb1, d + dB1);
        pa0 += 64; pa1 += 64; pb0 += 64; pb1 += 64;
        sb = (sb + 1) & 3;
    };

    // ---- frag read offsets (swizzled, conflict-free) ----
    int off_frag = (l & 15) * 64 + ((((l >> 4)) ^ (((l & 15) >> 1) & 3)) << 4);
    int a_off = wr * 8192 + off_frag;
    int b_off = 16384 + wc * 4096 + off_frag;

    f32x4 acc[8][4];
    #pragma unroll
    for (int m = 0; m < 8; ++m)
        #pragma unroll
        for (int n = 0; n < 4; ++n) acc[m][n] = (f32x4){0.f, 0.f, 0.f, 0.f};

    int cb = 0;
    STAGE(); STAGE(); STAGE();                     // tiles 0,1,2 in flight
    for (int kt = 0; kt < 61; ++kt) { STAGE(); KSTEP("12") }
    KSTEP("8") KSTEP("4") KSTEP("0")

    // ---- epilogue: silu(gate)*up; acc[m][n] n=0,1 gate, n=2,3 up ----
    int mbase = mb * BMT;
    #pragma unroll
    for (int m = 0; m < 8; ++m) {
        int rowl = wr * 128 + m * 16 + (l >> 4) * 4;
        #pragma unroll
        for (int np = 0; np < 2; ++np) {
            int col = nb * 128 + wc * 32 + np * 16 + (l & 15);
            #pragma unroll
            for (int r = 0; r < 4; ++r) {
                float gv = acc[m][np][r], uv = acc[m][np + 2][r];
                float av = gv / (1.f + __expf(-gv)) * uv;
                act[(size_t)(mbase + rowl + r) * D_INT + col] = f2bf(av);
            }
        }
    }
}

// ---------------- GEMM2: out[tok] += wt * (act @ Wd^T), K-split 2 ----------------
// grid 1152 = (8 nb x 2 ks) x 72 mb
__global__ void __launch_bounds__(512, 2)
k_g2(const unsigned short* __restrict__ act, const unsigned short* __restrict__ wd_b,
     const int* __restrict__ ptok, const float* __restrict__ pwt,
     const int* __restrict__ seg, float* __restrict__ out) {
    extern __shared__ char smem[];
    char* ldsw = smem; const char* ldsc = smem;
    int logical = xcd_logical(blockIdx.x, 1152);
    int pair = logical / MT2, mb = logical % MT2;
    int nb = pair >> 1, ks = pair & 1;
    if (mb * BMT >= seg[8]) return;
    int e = 0;
    #pragma unroll
    for (int j = 1; j < 8; ++j) if (seg[j] <= mb * BMT) e = j;
    int tid = threadIdx.x, w = tid >> 6, l = tid & 63;
    int wr = w >> 2, wc = w & 3;
    int koff = ks * 4096;                          // byte offset of K half

    int g = (l & 3) ^ ((l >> 3) & 3);
    int r0 = w * 16 + (l >> 2), r1 = 128 + r0;
    const char* pa0 = (const char*)act + (size_t)(mb * BMT + r0) * 8192 + koff + g * 16;
    const char* pa1 = (const char*)act + (size_t)(mb * BMT + r1) * 8192 + koff + g * 16;
    const char* wbase = (const char*)wd_b + (size_t)e * D_HID * 8192;
    const char* pb0 = wbase + (size_t)(nb * 256 + r0) * 8192 + koff + g * 16;
    const char* pb1 = wbase + (size_t)(nb * 256 + r1) * 8192 + koff + g * 16;
    int dA0 = w * 1024, dA1 = 8192 + w * 1024;
    int dB0 = 16384 + w * 1024, dB1 = 24576 + w * 1024;
    int sb = 0;
    auto STAGE = [&]() {
        char* d = ldsw + (sb << 15);
        gload_lds16(pa0, d + dA0); gload_lds16(pa1, d + dA1);
        gload_lds16(pb0, d + dB0); gload_lds16(pb1, d + dB1);
        pa0 += 64; pa1 += 64; pb0 += 64; pb1 += 64;
        sb = (sb + 1) & 3;
    };

    int off_frag = (l & 15) * 64 + ((((l >> 4)) ^ (((l & 15) >> 1) & 3)) << 4);
    int a_off = wr * 8192 + off_frag;
    int b_off = 16384 + wc * 4096 + off_frag;

    f32x4 acc[8][4];
    #pragma unroll
    for (int m = 0; m < 8; ++m)
        #pragma unroll
        for (int n = 0; n < 4; ++n) acc[m][n] = (f32x4){0.f, 0.f, 0.f, 0.f};

    int cb = 0;
    STAGE(); STAGE(); STAGE();
    for (int kt = 0; kt < 61; ++kt) { STAGE(); KSTEP("12") }
    KSTEP("8") KSTEP("4") KSTEP("0")

    // ---- epilogue: scaled atomic accumulate ----
    #pragma unroll
    for (int m = 0; m < 8; ++m) {
        int rowl = wr * 128 + m * 16 + (l >> 4) * 4;
        #pragma unroll
        for (int r = 0; r < 4; ++r) {
            int p = mb * BMT + rowl + r;
            int tok = ptok[p];
            float wt = pwt[p];
            if (tok >= 0) {
                #pragma unroll
                for (int n = 0; n < 4; ++n) {
                    int col = nb * 256 + wc * 64 + n * 16 + (l & 15);
                    unsafeAtomicAdd(&out[(size_t)tok * D_HID + col], wt * acc[m][n][r]);
                }
            }
        }
    }
}

extern "C" void kernel_launch(void* const* d_in, const int* in_sizes, int n_in,
                              void* d_out, int out_size, void* d_ws, size_t ws_size,
                              hipStream_t stream) {
    const float* x   = (const float*)d_in[0];
    const float* tw  = (const float*)d_in[2];
    const int*   te  = (const int*)d_in[3];
    const float* wgu = (const float*)d_in[4];
    const float* wd  = (const float*)d_in[5];
    float* out = (float*)d_out;
    char*  ws  = (char*)d_ws;

    int*   ptok   = (int*)(ws + OFF_PTOK);
    float* pwt    = (float*)(ws + OFF_PWT);
    int*   counts = (int*)(ws + OFF_CNT);
    int*   toff   = (int*)(ws + OFF_TOFF);
    int*   seg    = (int*)(ws + OFF_SEG);
    unsigned short* xb  = (unsigned short*)(ws + OFF_XB);
    unsigned short* act = (unsigned short*)(ws + OFF_ACT);
    unsigned short* w_b = (unsigned short*)(ws + OFF_W);   // wgu_b, then reused for wd_b

    hipFuncSetAttribute((const void*)k_g1, hipFuncAttributeMaxDynamicSharedMemorySize, 131072);
    hipFuncSetAttribute((const void*)k_g2, hipFuncAttributeMaxDynamicSharedMemorySize, 131072);

    k_prep<<<8192, 256, 0, stream>>>(x, xb, out);
    k_count<<<N_EXP, 256, 0, stream>>>(te, counts, toff);
    k_fill<<<N_EXP, 256, 0, stream>>>(te, tw, counts, toff, ptok, pwt, seg);

    // wgu -> bf16 (33,554,432 float4 -> 131072 blocks), GEMM1
    k_cast<<<131072, 256, 0, stream>>>(wgu, w_b);
    k_g1<<<2304, 512, 131072, stream>>>(xb, w_b, ptok, seg, act);
    // wd -> bf16 (16,777,216 float4 -> 65536 blocks), GEMM2
    k_cast<<<65536, 256, 0, stream>>>(wd, w_b);
    k_g2<<<1152, 512, 131072, stream>>>(act, w_b, ptok, pwt, seg, out);
}

// Round 6
// 1263.613 us; speedup vs baseline: 1.0145x; 1.0145x over previous
//
#include <hip/hip_runtime.h>
#include <stdint.h>

// ---------------- problem constants ----------------
#define T_TOKENS 4096
#define D_HID    2048
#define D_INT    4096
#define N_EXP    8
#define TOPK     4
#define NFLAT    (T_TOKENS*TOPK)      // 16384 routed pairs
#define BMT      256                  // M tile
#define MAXPAD   (NFLAT + N_EXP*BMT)  // 18432 worst-case padded rows
#define MT2      (MAXPAD/BMT)         // 72 M-tiles

// ---------------- ws layout (bytes) ----------------
#define OFF_PTOK 0ull
#define OFF_PWT  73728ull
#define OFF_CNT  147456ull
#define OFF_TOFF 147712ull
#define OFF_SEG  155904ull
#define OFF_XB   262144ull                  // 4096*2048*2 = 16,777,216
#define OFF_ACT  17039360ull                // 18432*4096*2 = 150,994,944
#define OFF_W    168034304ull               // max(wgu_b 256MB, wd_b 128MB)

typedef float f32x4  __attribute__((ext_vector_type(4)));
typedef short bf16x8 __attribute__((ext_vector_type(8)));

__device__ __forceinline__ unsigned short f2bf(float f) {
    unsigned int u = __float_as_uint(f);
    u += 0x7fffu + ((u >> 16) & 1u);      // RNE
    return (unsigned short)(u >> 16);
}

__device__ __forceinline__ void gload_lds16(const void* g, void* l) {
    __builtin_amdgcn_global_load_lds((const __attribute__((address_space(1))) void*)g,
                                     (__attribute__((address_space(3))) void*)l,
                                     16, 0, 0);
}

// XCD-bijective chunk swizzle (m204)
__device__ __forceinline__ int xcd_logical(int hw, int nwg) {
    int q = nwg >> 3, r = nwg & 7;
    int xc = hw & 7, sl = hw >> 3;
    return (xc < r ? xc * (q + 1) : r * (q + 1) + (xc - r) * q) + sl;
}

// ---------------- kernel 0: cast x -> bf16, zero out ----------------
__global__ void k_prep(const float* __restrict__ x, unsigned short* __restrict__ xb,
                       float* __restrict__ out) {
    int i = blockIdx.x * 256 + threadIdx.x;          // float4 units, exact grid (8192)
    float4 v = ((const float4*)x)[i];
    ushort4 h;
    h.x = f2bf(v.x); h.y = f2bf(v.y); h.z = f2bf(v.z); h.w = f2bf(v.w);
    ((ushort4*)xb)[i] = h;
    ((float4*)out)[i] = make_float4(0.f, 0.f, 0.f, 0.f);
}

// ---------------- generic fp32 -> bf16 cast (grid = n4/256) ----------------
__global__ void k_cast(const float* __restrict__ src, unsigned short* __restrict__ dst) {
    size_t i = (size_t)blockIdx.x * 256 + threadIdx.x;   // float4 index
    float4 v = ((const float4*)src)[i];
    ushort4 h;
    h.x = f2bf(v.x); h.y = f2bf(v.y); h.z = f2bf(v.z); h.w = f2bf(v.w);
    ((ushort4*)dst)[i] = h;
}

// ---------------- routing: deterministic compaction ----------------
__global__ void k_count(const int* __restrict__ te, int* __restrict__ counts,
                        int* __restrict__ toff) {
    int e = blockIdx.x, t = threadIdx.x;
    int cnt = 0;
    int base = t * 64;
    for (int i = 0; i < 64; i++) cnt += (te[base + i] == e);
    __shared__ int s[256];
    s[t] = cnt; __syncthreads();
    int incl = cnt;
    for (int off = 1; off < 256; off <<= 1) {
        int tmp = (t >= off) ? s[t - off] : 0;
        __syncthreads();
        incl += tmp; s[t] = incl;
        __syncthreads();
    }
    toff[e * 256 + t] = incl - cnt;
    if (t == 255) counts[e] = incl;
}

__global__ void k_fill(const int* __restrict__ te, const float* __restrict__ tw,
                       const int* __restrict__ counts, const int* __restrict__ toff,
                       int* __restrict__ ptok, float* __restrict__ pwt, int* __restrict__ seg) {
    int e = blockIdx.x, t = threadIdx.x;
    int segs[9]; int a = 0;
    #pragma unroll
    for (int j = 0; j < 8; j++) { segs[j] = a; a += (counts[j] + BMT - 1) & ~(BMT - 1); }
    segs[8] = a;
    if (e == 0 && t == 0) { for (int j = 0; j < 9; j++) seg[j] = segs[j]; }
    int base = segs[e] + toff[e * 256 + t];
    int rank = 0;
    for (int i = t * 64; i < (t + 1) * 64; i++) {
        if (te[i] == e) { ptok[base + rank] = i >> 2; pwt[base + rank] = tw[i]; rank++; }
    }
    int cnt = counts[e], pc = (cnt + BMT - 1) & ~(BMT - 1);
    for (int i = cnt + t; i < pc; i += 256) { ptok[segs[e] + i] = -1; pwt[segs[e] + i] = 0.f; }
}

// =====================================================================
// Round-6 GEMM core: 256 threads (4 waves, 2 wr x 2 wc), wave C = 128x64,
// BK=32, 3-slot LDS ring of 24 KiB (A 16K: 256 rows x 64B; B 8K: 128 rows),
// prefetch distance 2 -> steady vmcnt(12). 72 KiB LDS/block, <=256 regs
// => TWO independent blocks per CU: one block's LDS-read storm overlaps
// the other block's MFMA phase (desynced barriers).
// Slot-reuse proof: STAGE(kt+2) writes slot (kt+2)%3, last read at step
// kt-1 whose reads completed before that step's lgkmcnt(0)+barrier2.
// Swizzle (validated zero-conflict): LDS chunk-slot s of row r holds data
// chunk s^((r>>1)&3); stage src chunk g=(l&3)^((l>>3)&3); read chunk
// (l>>4)^(((l&15)>>1)&3).
// =====================================================================

#define MFMA_2M(M0, M1) \
    _Pragma("unroll") for (int n_ = 0; n_ < 4; ++n_) \
        acc[M0][n_] = __builtin_amdgcn_mfma_f32_16x16x32_bf16(af[M0], bf[n_], acc[M0][n_], 0, 0, 0); \
    _Pragma("unroll") for (int n_ = 0; n_ < 4; ++n_) \
        acc[M1][n_] = __builtin_amdgcn_mfma_f32_16x16x32_bf16(af[M1], bf[n_], acc[M1][n_], 0, 0, 0);

#define KSTEP(VMS) \
  asm volatile("s_waitcnt vmcnt(" VMS ")" ::: "memory"); \
  __builtin_amdgcn_s_barrier(); \
  __builtin_amdgcn_sched_barrier(0); \
  { \
    const char* pT = ldsc + cb * 24576; \
    bf16x8 af[8], bf[4]; \
    _Pragma("unroll") for (int n_ = 0; n_ < 4; ++n_) \
        bf[n_] = *(const bf16x8*)(pT + b_off + n_ * 1024); \
    af[0] = *(const bf16x8*)(pT + a_off); \
    af[1] = *(const bf16x8*)(pT + a_off + 1024); \
    __builtin_amdgcn_sched_barrier(0); \
    _Pragma("unroll") for (int m_ = 2; m_ < 8; ++m_) \
        af[m_] = *(const bf16x8*)(pT + a_off + m_ * 1024); \
    __builtin_amdgcn_sched_barrier(0); \
    asm volatile("s_waitcnt lgkmcnt(6)" ::: "memory"); \
    __builtin_amdgcn_sched_barrier(0); \
    __builtin_amdgcn_s_setprio(1); \
    MFMA_2M(0, 1) \
    __builtin_amdgcn_s_setprio(0); \
    asm volatile("s_waitcnt lgkmcnt(4)" ::: "memory"); \
    __builtin_amdgcn_sched_barrier(0); \
    __builtin_amdgcn_s_setprio(1); \
    MFMA_2M(2, 3) \
    __builtin_amdgcn_s_setprio(0); \
    asm volatile("s_waitcnt lgkmcnt(2)" ::: "memory"); \
    __builtin_amdgcn_sched_barrier(0); \
    __builtin_amdgcn_s_setprio(1); \
    MFMA_2M(4, 5) \
    __builtin_amdgcn_s_setprio(0); \
    asm volatile("s_waitcnt lgkmcnt(0)" ::: "memory"); \
    __builtin_amdgcn_sched_barrier(0); \
    __builtin_amdgcn_s_barrier(); \
    __builtin_amdgcn_s_setprio(1); \
    MFMA_2M(6, 7) \
    __builtin_amdgcn_s_setprio(0); \
    cb = (cb == 2) ? 0 : cb + 1; \
  }

// ---------------- GEMM1: act = silu(gate)*up, h = xb @ Wgu^T ----------------
// block: 256 tokens x 64 inter-cols (=128 weight rows). grid 4608 = 64 nb x 72 mb
__global__ void __launch_bounds__(256, 2)
k_g1(const unsigned short* __restrict__ xb, const unsigned short* __restrict__ wgu_b,
     const int* __restrict__ ptok, const int* __restrict__ seg,
     unsigned short* __restrict__ act) {
    extern __shared__ char smem[];
    char* ldsw = smem; const char* ldsc = smem;
    int logical = xcd_logical(blockIdx.x, 4608);
    int nb = logical / MT2, mb = logical % MT2;
    if (mb * BMT >= seg[8]) return;
    int e = 0;
    #pragma unroll
    for (int j = 1; j < 8; ++j) if (seg[j] <= mb * BMT) e = j;
    int tid = threadIdx.x, w = tid >> 6, l = tid & 63;
    int wr = w >> 1, wc = w & 1;

    // ---- stage setup: 6 gloads/thread/K-tile (A 4, B 2) ----
    int g = (l & 3) ^ ((l >> 3) & 3);            // pre-swizzled source chunk
    const char* pa[4]; const char* pb[2];
    #pragma unroll
    for (int i = 0; i < 4; ++i) {
        int r = i * 64 + w * 16 + (l >> 2);      // A row 0..255
        int tok = ptok[mb * BMT + r]; if (tok < 0) tok = 0;
        pa[i] = (const char*)xb + (size_t)tok * 4096 + g * 16;
    }
    const char* wbase = (const char*)wgu_b + (size_t)e * 8192 * 4096;
    #pragma unroll
    for (int j = 0; j < 2; ++j) {
        int r = j * 64 + w * 16 + (l >> 2);      // B row 0..127
        int wcr = r >> 6, jj = r & 63;
        int grow = (jj < 32) ? (nb * 64 + wcr * 32 + jj)
                             : (D_INT + nb * 64 + wcr * 32 + jj - 32);
        pb[j] = wbase + (size_t)grow * 4096 + g * 16;
    }
    int sb = 0;
    auto STAGE = [&]() {
        char* d = ldsw + sb * 24576;
        gload_lds16(pa[0], d + w * 1024);
        gload_lds16(pa[1], d + 4096 + w * 1024);
        gload_lds16(pa[2], d + 8192 + w * 1024);
        gload_lds16(pa[3], d + 12288 + w * 1024);
        gload_lds16(pb[0], d + 16384 + w * 1024);
        gload_lds16(pb[1], d + 20480 + w * 1024);
        pa[0] += 64; pa[1] += 64; pa[2] += 64; pa[3] += 64;
        pb[0] += 64; pb[1] += 64;
        sb = (sb == 2) ? 0 : sb + 1;
    };

    // ---- frag read offsets (swizzled, conflict-free) ----
    int off_frag = (l & 15) * 64 + ((((l >> 4)) ^ (((l & 15) >> 1) & 3)) << 4);
    int a_off = wr * 8192 + off_frag;
    int b_off = 16384 + wc * 4096 + off_frag;

    f32x4 acc[8][4];
    #pragma unroll
    for (int m = 0; m < 8; ++m)
        #pragma unroll
        for (int n = 0; n < 4; ++n) acc[m][n] = (f32x4){0.f, 0.f, 0.f, 0.f};

    int cb = 0;
    STAGE(); STAGE();                              // tiles 0,1 in flight (12 loads)
    for (int kt = 0; kt < 62; ++kt) { STAGE(); KSTEP("12") }
    KSTEP("6") KSTEP("0")

    // ---- epilogue: silu(gate)*up; acc n=0,1 gate, n=2,3 up ----
    int mbase = mb * BMT;
    #pragma unroll
    for (int m = 0; m < 8; ++m) {
        int rowl = wr * 128 + m * 16 + (l >> 4) * 4;
        #pragma unroll
        for (int np = 0; np < 2; ++np) {
            int col = nb * 64 + wc * 32 + np * 16 + (l & 15);
            #pragma unroll
            for (int r = 0; r < 4; ++r) {
                float gv = acc[m][np][r], uv = acc[m][np + 2][r];
                float av = gv / (1.f + __expf(-gv)) * uv;
                act[(size_t)(mbase + rowl + r) * D_INT + col] = f2bf(av);
            }
        }
    }
}

// ---------------- GEMM2: out[tok] += wt * (act @ Wd^T), K-split 2 ----------------
// block: 256 tokens x 128 out-cols. grid 2304 = (16 nb x 2 ks) x 72 mb
__global__ void __launch_bounds__(256, 2)
k_g2(const unsigned short* __restrict__ act, const unsigned short* __restrict__ wd_b,
     const int* __restrict__ ptok, const float* __restrict__ pwt,
     const int* __restrict__ seg, float* __restrict__ out) {
    extern __shared__ char smem[];
    char* ldsw = smem; const char* ldsc = smem;
    int logical = xcd_logical(blockIdx.x, 2304);
    int pair = logical / MT2, mb = logical % MT2;
    int nb = pair >> 1, ks = pair & 1;
    if (mb * BMT >= seg[8]) return;
    int e = 0;
    #pragma unroll
    for (int j = 1; j < 8; ++j) if (seg[j] <= mb * BMT) e = j;
    int tid = threadIdx.x, w = tid >> 6, l = tid & 63;
    int wr = w >> 1, wc = w & 1;
    int koff = ks * 4096;                          // byte offset of K half (2048 elems)

    int g = (l & 3) ^ ((l >> 3) & 3);
    const char* pa[4]; const char* pb[2];
    #pragma unroll
    for (int i = 0; i < 4; ++i) {
        int r = i * 64 + w * 16 + (l >> 2);
        pa[i] = (const char*)act + (size_t)(mb * BMT + r) * 8192 + koff + g * 16;
    }
    const char* wbase = (const char*)wd_b + (size_t)e * D_HID * 8192;
    #pragma unroll
    for (int j = 0; j < 2; ++j) {
        int r = j * 64 + w * 16 + (l >> 2);
        pb[j] = wbase + (size_t)(nb * 128 + r) * 8192 + koff + g * 16;
    }
    int sb = 0;
    auto STAGE = [&]() {
        char* d = ldsw + sb * 24576;
        gload_lds16(pa[0], d + w * 1024);
        gload_lds16(pa[1], d + 4096 + w * 1024);
        gload_lds16(pa[2], d + 8192 + w * 1024);
        gload_lds16(pa[3], d + 12288 + w * 1024);
        gload_lds16(pb[0], d + 16384 + w * 1024);
        gload_lds16(pb[1], d + 20480 + w * 1024);
        pa[0] += 64; pa[1] += 64; pa[2] += 64; pa[3] += 64;
        pb[0] += 64; pb[1] += 64;
        sb = (sb == 2) ? 0 : sb + 1;
    };

    int off_frag = (l & 15) * 64 + ((((l >> 4)) ^ (((l & 15) >> 1) & 3)) << 4);
    int a_off = wr * 8192 + off_frag;
    int b_off = 16384 + wc * 4096 + off_frag;

    f32x4 acc[8][4];
    #pragma unroll
    for (int m = 0; m < 8; ++m)
        #pragma unroll
        for (int n = 0; n < 4; ++n) acc[m][n] = (f32x4){0.f, 0.f, 0.f, 0.f};

    int cb = 0;
    STAGE(); STAGE();
    for (int kt = 0; kt < 62; ++kt) { STAGE(); KSTEP("12") }
    KSTEP("6") KSTEP("0")

    // ---- epilogue: scaled atomic accumulate ----
    #pragma unroll
    for (int m = 0; m < 8; ++m) {
        int rowl = wr * 128 + m * 16 + (l >> 4) * 4;
        #pragma unroll
        for (int r = 0; r < 4; ++r) {
            int p = mb * BMT + rowl + r;
            int tok = ptok[p];
            float wt = pwt[p];
            if (tok >= 0) {
                #pragma unroll
                for (int n = 0; n < 4; ++n) {
                    int col = nb * 128 + wc * 64 + n * 16 + (l & 15);
                    unsafeAtomicAdd(&out[(size_t)tok * D_HID + col], wt * acc[m][n][r]);
                }
            }
        }
    }
}

extern "C" void kernel_launch(void* const* d_in, const int* in_sizes, int n_in,
                              void* d_out, int out_size, void* d_ws, size_t ws_size,
                              hipStream_t stream) {
    const float* x   = (const float*)d_in[0];
    const float* tw  = (const float*)d_in[2];
    const int*   te  = (const int*)d_in[3];
    const float* wgu = (const float*)d_in[4];
    const float* wd  = (const float*)d_in[5];
    float* out = (float*)d_out;
    char*  ws  = (char*)d_ws;

    int*   ptok   = (int*)(ws + OFF_PTOK);
    float* pwt    = (float*)(ws + OFF_PWT);
    int*   counts = (int*)(ws + OFF_CNT);
    int*   toff   = (int*)(ws + OFF_TOFF);
    int*   seg    = (int*)(ws + OFF_SEG);
    unsigned short* xb  = (unsigned short*)(ws + OFF_XB);
    unsigned short* act = (unsigned short*)(ws + OFF_ACT);
    unsigned short* w_b = (unsigned short*)(ws + OFF_W);   // wgu_b, then reused for wd_b

    hipFuncSetAttribute((const void*)k_g1, hipFuncAttributeMaxDynamicSharedMemorySize, 73728);
    hipFuncSetAttribute((const void*)k_g2, hipFuncAttributeMaxDynamicSharedMemorySize, 73728);

    k_prep<<<8192, 256, 0, stream>>>(x, xb, out);
    k_count<<<N_EXP, 256, 0, stream>>>(te, counts, toff);
    k_fill<<<N_EXP, 256, 0, stream>>>(te, tw, counts, toff, ptok, pwt, seg);

    // wgu -> bf16 (33,554,432 float4 -> 131072 blocks), GEMM1
    k_cast<<<131072, 256, 0, stream>>>(wgu, w_b);
    k_g1<<<4608, 256, 73728, stream>>>(xb, w_b, ptok, seg, act);
    // wd -> bf16 (16,777,216 float4 -> 65536 blocks), GEMM2
    k_cast<<<65536, 256, 0, stream>>>(wd, w_b);
    k_g2<<<2304, 256, 73728, stream>>>(act, w_b, ptok, pwt, seg, out);
}